// Round 2
// baseline (242.151 us; speedup 1.0000x reference)
//
#include <hip/hip_runtime.h>
#include <math.h>
#include <stdint.h>

#define NB 15
#define TROWS 512                 // rows per tile (2 per thread)
#define TBYTES (TROWS * 40)       // 20480 B logits per tile
#define LBYTES (TROWS * 4)        // 2048 B labels per tile
#define NCOPY 8                   // spread accumulator copies (contention /8)
#define ACCSTRIDE 64              // floats per copy (line-separated)

// d_ws: NCOPY copies of [0..14]=counts, [15..29]=sum_u, [30..44]=sum_err

__device__ __forceinline__ void gload_lds16(const void* g, void* ldsBase, uint32_t ldsByteOff)
{
    // async global->LDS, 16 B/lane; LDS dest = wave-uniform base + lane*16 (HW)
    __builtin_amdgcn_global_load_lds(
        (const __attribute__((address_space(1))) uint32_t*)g,
        (__attribute__((address_space(3))) uint32_t*)((char*)ldsBase + ldsByteOff),
        16, 0, 0);
}

__device__ __forceinline__ void gload_lds4(const void* g, void* ldsBase, uint32_t ldsByteOff)
{
    __builtin_amdgcn_global_load_lds(
        (const __attribute__((address_space(1))) uint32_t*)g,
        (__attribute__((address_space(3))) uint32_t*)((char*)ldsBase + ldsByteOff),
        4, 0, 0);
}

__device__ __forceinline__ void row_stats(const float lv[10], float lvl_lab, bool rowOK,
                                          int& bin, float& u, int& e10)
{
    float m = lv[0];
#pragma unroll
    for (int j = 1; j < 10; ++j) m = fmaxf(m, lv[j]);

    const float c = 1.44269504088896340736f;
    float mc = m * c;
    float Z = 0.0f, S = 0.0f;
#pragma unroll
    for (int j = 0; j < 10; ++j) {
        float e = exp2f(fmaf(lv[j], c, -mc));
        Z += e;
        S = fmaf(e, e, S);
    }
    float ratio = S * __builtin_amdgcn_rcpf(Z * Z);   // sum(p^2)
    u = -log2f(ratio + 1e-12f);

    bool valid = rowOK && (u >= 0.0f) && (u < 1.0f);  // LDS garbage rows gated by rowOK
    bin = -1;
    if (valid) {
        bin = (int)(u * 15.0f);
        if (bin > 14) bin = 14;
    }
    if (!valid) u = 0.0f;
    e10 = (lvl_lab != m) ? 1 : 0;     // wrong iff label's logit isn't the max
}

__global__ __launch_bounds__(256) void bin_kernel(
    const float* __restrict__ logits,
    const int* __restrict__ labels,
    float* __restrict__ acc,
    int N, int numTiles)
{
    // Double-buffered tiles: DMA for tile t+1 overlaps compute on tile t.
    // Counted vmcnt (never 0 in steady state) + raw s_barrier -> no full drains.
    __shared__ float ldsLog[2][TROWS * 10];   // 2 x 20480 B
    __shared__ int   ldsLab[2][TROWS];        // 2 x 2048 B
    __shared__ float s_acc[3 * NB];

    const int t = threadIdx.x;
    if (t < 3 * NB) s_acc[t] = 0.0f;
    const int wid  = t >> 6;
    const int lane = t & 63;

    int   pk[NB];                          // count | (err<<16)
    float su[NB];
#pragma unroll
    for (int b = 0; b < NB; ++b) { pk[b] = 0; su[b] = 0.0f; }

    const char* srcB = (const char*)logits;
    const char* labB = (const char*)labels;
    const long long totB  = (long long)N * 40;
    const long long ltotB = (long long)N * 4;

    // Each wave issues EXACTLY 7 VMEM ops per stage (5x1KB logits + 2x256B labels),
    // tail tiles clamp the global address instead of skipping, so vmcnt counting
    // stays uniform. No other VMEM ops exist in the loop body.
    auto stage = [&](int buf, long long tl) {
#pragma unroll
        for (int k = 0; k < 5; ++k) {
            uint32_t loff = (uint32_t)(wid * 5 + k) << 10;     // wave-uniform
            long long gb = tl * TBYTES + loff + lane * 16;
            if (gb > totB - 16) gb = totB - 16;                // clamp, never skip
            gload_lds16(srcB + gb, &ldsLog[buf][0], __builtin_amdgcn_readfirstlane(loff));
        }
#pragma unroll
        for (int k = 0; k < 2; ++k) {
            uint32_t loff = (uint32_t)(wid * 2 + k) << 8;      // wave-uniform
            long long gb = tl * LBYTES + loff + lane * 4;
            if (gb > ltotB - 4) gb = ltotB - 4;
            gload_lds4(labB + gb, &ldsLab[buf][0], __builtin_amdgcn_readfirstlane(loff));
        }
    };

    long long tile = blockIdx.x;          // grid <= numTiles, prologue tile valid
    stage(0, tile);                       // prologue: tile0 -> buf0, no wait
    int cur = 0;

    for (; tile < numTiles; tile += gridDim.x) {
        const long long nxt = tile + gridDim.x;
        const bool hasNext = (nxt < numTiles);          // block-uniform
        if (hasNext) {
            stage(cur ^ 1, nxt);                        // issue next tile (7 loads/wave)
            // wait only until the CURRENT tile's 7 loads retired; next tile's
            // 7 stay in flight across the barrier (in-order vmcnt retirement)
            asm volatile("s_waitcnt vmcnt(7)" ::: "memory");
        } else {
            asm volatile("s_waitcnt vmcnt(0)" ::: "memory");
        }
        __builtin_amdgcn_s_barrier();                   // all waves' DMA for cur landed

        const float* L  = ldsLog[cur];
        const int*   LB = ldsLab[cur];

        const int r0 = (int)tile * TROWS + t;
        const int r1 = r0 + 256;
        int lab0 = LB[t];       lab0 = lab0 < 0 ? 0 : (lab0 > 9 ? 9 : lab0);
        int lab1 = LB[t + 256]; lab1 = lab1 < 0 ? 0 : (lab1 > 9 ? 9 : lab1);

        // ---- two rows per thread ----
        float a[10], b2[10];
        {
            const float2* p = (const float2*)(L + t * 10);
#pragma unroll
            for (int j = 0; j < 5; ++j) { float2 w = p[j]; a[2*j] = w.x; a[2*j+1] = w.y; }
        }
        {
            const float2* p = (const float2*)(L + (t + 256) * 10);
#pragma unroll
            for (int j = 0; j < 5; ++j) { float2 w = p[j]; b2[2*j] = w.x; b2[2*j+1] = w.y; }
        }
        float lvl0 = L[t * 10 + lab0];           // label logit, dynamic LDS read
        float lvl1 = L[(t + 256) * 10 + lab1];

        int binA, eA, binB, eB;
        float uA, uB;
        row_stats(a,  lvl0, r0 < N, binA, uA, eA);
        row_stats(b2, lvl1, r1 < N, binB, uB, eB);

        int incA = 1 + (eA << 16);
        int incB = 1 + (eB << 16);
#pragma unroll
        for (int b = 0; b < NB; ++b) {
            bool mA = (binA == b);
            bool mB = (binB == b);
            pk[b] += (mA ? incA : 0) + (mB ? incB : 0);
            su[b] += (mA ? uA : 0.0f) + (mB ? uB : 0.0f);
        }

        // all LDS reads already consumed; cheap drain keeps the trailing barrier honest
        asm volatile("s_waitcnt lgkmcnt(0)" ::: "memory");
        __builtin_amdgcn_s_barrier();               // cur free to be overwritten next iter
        cur ^= 1;
    }

    // ---- once-per-block: wave butterfly -> shared atomics -> spread global atomics
#pragma unroll
    for (int b = 0; b < NB; ++b) {
        int   p = pk[b];
        float s = su[b];
#pragma unroll
        for (int off = 1; off < 64; off <<= 1) {
            p += __shfl_xor(p, off, 64);
            s += __shfl_xor(s, off, 64);
        }
        if (lane == 0) {
            atomicAdd(&s_acc[b],          (float)(p & 0xFFFF));
            atomicAdd(&s_acc[NB + b],     s);
            atomicAdd(&s_acc[2 * NB + b], (float)(p >> 16));
        }
    }
    __syncthreads();
    if (t < 3 * NB) {
        float v = s_acc[t];
        if (v != 0.0f)
            atomicAdd(&acc[(blockIdx.x & (NCOPY - 1)) * ACCSTRIDE + t], v);
    }
}

__global__ void finalize_kernel(const float* __restrict__ acc,
                                float* __restrict__ out, float n)
{
    int b = threadIdx.x;
    float gap = 0.0f;
    if (b < NB) {
        float cnt = 0.0f, sumu = 0.0f, serr = 0.0f;
#pragma unroll
        for (int c = 0; c < NCOPY; ++c) {
            cnt  += acc[c * ACCSTRIDE + b];
            sumu += acc[c * ACCSTRIDE + NB + b];
            serr += acc[c * ACCSTRIDE + 2 * NB + b];
        }
        if (cnt > 0.0f) {
            float u_b   = sumu / cnt;
            float err_b = serr / cnt;
            float inner = 2.0f * exp2f(-u_b) - 1.0f;
            if (inner < 0.0f) inner = 0.0f;
            float r_ref = 0.5f * (1.0f - sqrtf(inner));
            gap = fabsf(err_b - r_ref) * (cnt / n);
        }
    }
#pragma unroll
    for (int off = 32; off >= 1; off >>= 1)
        gap += __shfl_xor(gap, off, 64);
    if (b == 0) out[0] = gap;
}

extern "C" void kernel_launch(void* const* d_in, const int* in_sizes, int n_in,
                              void* d_out, int out_size, void* d_ws, size_t ws_size,
                              hipStream_t stream)
{
    const float* logits = (const float*)d_in[0];
    const int*   labels = (const int*)d_in[1];
    const int N = in_sizes[1];                  // labels count = number of rows

    float* acc = (float*)d_ws;                  // NCOPY * ACCSTRIDE floats
    hipMemsetAsync(acc, 0, NCOPY * ACCSTRIDE * sizeof(float), stream);

    const int numTiles = (N + TROWS - 1) / TROWS;
    // ~45.4 KB LDS -> 3 blocks/CU resident; 768 = 3*256 persistent-ish blocks,
    // ~10 tiles each so the un-overlapped prologue amortizes to <10%.
    int blocks = numTiles < 768 ? numTiles : 768;
    bin_kernel<<<blocks, 256, 0, stream>>>(logits, labels, acc, N, numTiles);
    finalize_kernel<<<1, 64, 0, stream>>>(acc, (float*)d_out, (float)N);
}